// Round 8
// baseline (266.844 us; speedup 1.0000x reference)
//
#include <hip/hip_runtime.h>

#define BB     128
#define MM     4096
#define NN     8192
#define DEG    12
#define RDEG   11          // edges 0..10 real; edge 11 is ALWAYS the dummy (col==NN)
#define MAXIT  8
#define BLOCK  1024
#define RPT    (MM / BLOCK)
#define NW     (NN / 2)    // l_v packed: 2 vars per word, u16 halves biased +32768
#define BIAS   32768
#define BIG    (1 << 20)

__device__ __forceinline__ int quantI(float x) {   // fp2fxp -> integer units of 1/16
    float r = rintf(x * 16.0f);                    // RNE, matches jnp.round
    r = fminf(r, 127.0f);
    r = fmaxf(r, -128.0f);
    return (int)r;
}
__device__ __forceinline__ int clamp8(int t) { return max(-128, min(127, t)); }
__device__ __forceinline__ int rne4(int t) {       // RNE of t/16, t >= 0
    const int r = t >> 4, rem = t & 15;
    return r + (((rem > 8) || (rem == 8 && (r & 1))) ? 1 : 0);
}

#define EX_COL(KK, D) ((int)((colp[KK][(D) >> 1] >> (((D) & 1) * 16)) & 0xffffu))

// Issue all 11 gathers of row KK (ds_read_u16 from a compile-time-distinct buffer).
#define ISSUE(KK, LU, CURS) \
    _Pragma("unroll") for (int d = 0; d < RDEG; ++d) { LU[d] = (int)CURS[EX_COL(KK, d)]; }

// One check-row (it >= 2): min-sum from prefetched LU, then (via __VA_ARGS__)
// issue the NEXT row's gathers BEFORE this row's atomics. Reads target CURA,
// atomics target NXTA -- distinct named LDS objects, so the scheduler may
// overlap them freely (the whole point of this round).
#define ROW(KK, LU, NXTA, FBI, FB1, ...) do {                                  \
    int par = 0, sbits = 0, min0 = BIG, min1 = BIG;                            \
    int aa[RDEG];                                                              \
    _Pragma("unroll") for (int d = 0; d < RDEG; ++d) {                         \
        const int m = (int)(signed char)((msgp[KK][d >> 2] >> ((d & 3) * 8)) & 0xffu); \
        const int l = LU[d] - BIAS;                                            \
        par ^= (l <= 0) ? 1 : 0;                                               \
        const int av = clamp8(l - m);                                          \
        const int t = abs(av);                                                 \
        sbits |= ((av <= 0) ? 1 : 0) << d;                                     \
        min1 = min(min1, max(min0, t)); min0 = min(min0, t);                   \
        aa[d] = t; }                                                           \
    /* dummy edge a = fxp(inf-0) = 7.9375 -> 127 joins mins AND clamps both */ \
    min1 = min(min1, max(min0, 127)); min0 = min(min0, 127);                   \
    mism |= par ^ ((synbits >> KK) & 1);                                       \
    int eqb = 0;                                                               \
    _Pragma("unroll") for (int d = 0; d < RDEG; ++d)                           \
        eqb |= ((aa[d] == min0) ? 1 : 0) << d;                                 \
    __VA_ARGS__;                                                               \
    const int qsb = ((synbits >> KK) & 1) ^ (__popc(sbits) & 1);               \
    const int q0 = FB1 ? min0 : rne4(min0 * FBI);                              \
    const int q1 = FB1 ? min1 : rne4(min1 * FBI);                              \
    unsigned nm0 = 0u, nm1 = 0u, nm2 = 0u;                                     \
    _Pragma("unroll") for (int d = 0; d < RDEG; ++d) {                         \
        const int q = ((eqb >> d) & 1) ? q1 : q0;                              \
        const int s = ((sbits >> d) & 1) ^ qsb;                                \
        const int bv = s ? -q : q;                                             \
        if (d < 4)      nm0 |= ((unsigned)bv & 0xffu) << (d * 8);              \
        else if (d < 8) nm1 |= ((unsigned)bv & 0xffu) << ((d - 4) * 8);        \
        else            nm2 |= ((unsigned)bv & 0xffu) << ((d - 8) * 8);        \
        if (bv != 0) {                                                         \
            const int col = EX_COL(KK, d);                                     \
            atomicAdd(&NXTA[col >> 1], (int)((unsigned)bv << ((col & 1) << 4))); } } \
    msgp[KK][0] = nm0; msgp[KK][1] = nm1; msgp[KK][2] = nm2;                   \
} while (0)

// it == 1: a = message0 (already in msgp); no gathers, no parity, dummy = +inf
// (excluded from mins); scatter b1 into lvB (pre-filled with u0).
#define ROW1(KK) do {                                                          \
    int sbits = 0, min0 = BIG, min1 = BIG;                                     \
    int aa[RDEG];                                                              \
    _Pragma("unroll") for (int d = 0; d < RDEG; ++d) {                         \
        const int m = (int)(signed char)((msgp[KK][d >> 2] >> ((d & 3) * 8)) & 0xffu); \
        const int t = abs(m);                                                  \
        sbits |= ((m <= 0) ? 1 : 0) << d;                                      \
        min1 = min(min1, max(min0, t)); min0 = min(min0, t);                   \
        aa[d] = t; }                                                           \
    int eqb = 0;                                                               \
    _Pragma("unroll") for (int d = 0; d < RDEG; ++d)                           \
        eqb |= ((aa[d] == min0) ? 1 : 0) << d;                                 \
    const int qsb = ((synbits >> KK) & 1) ^ (__popc(sbits) & 1);               \
    const int m0C = min(min0, 127), m1C = min(min1, 127);                      \
    const int q0 = rne4(m0C * 8);                                              \
    const int q1 = rne4(m1C * 8);                                              \
    unsigned nm0 = 0u, nm1 = 0u, nm2 = 0u;                                     \
    _Pragma("unroll") for (int d = 0; d < RDEG; ++d) {                         \
        const int q = ((eqb >> d) & 1) ? q1 : q0;                              \
        const int s = ((sbits >> d) & 1) ^ qsb;                                \
        const int bv = s ? -q : q;                                             \
        if (d < 4)      nm0 |= ((unsigned)bv & 0xffu) << (d * 8);              \
        else if (d < 8) nm1 |= ((unsigned)bv & 0xffu) << ((d - 4) * 8);        \
        else            nm2 |= ((unsigned)bv & 0xffu) << ((d - 8) * 8);        \
        if (bv != 0) {                                                         \
            const int col = EX_COL(KK, d);                                     \
            atomicAdd(&lvB[col >> 1], (int)((unsigned)bv << ((col & 1) << 4))); } } \
    msgp[KK][0] = nm0; msgp[KK][1] = nm1; msgp[KK][2] = nm2;                   \
} while (0)

// One full iteration (it >= 2), buffers bound at compile time.
// Reset of RSTA is hoisted to the head so its write retires under the compute.
#define ITER(IT, CURA, NXTA, RSTA, FBI, FB1) {                                 \
    const unsigned short* curS = (const unsigned short*)CURA;                  \
    int mism = 0;                                                              \
    int lu0[RDEG], lu1[RDEG];                                                  \
    ISSUE(0, lu0, curS);                                                       \
    ((int4*)RSTA)[tid] = make_int4(u0a, u0b, u0c, u0d);                        \
    ROW(0, lu0, NXTA, FBI, FB1, ISSUE(1, lu1, curS));                          \
    ROW(1, lu1, NXTA, FBI, FB1, ISSUE(2, lu0, curS));                          \
    ROW(2, lu0, NXTA, FBI, FB1, ISSUE(3, lu1, curS));                          \
    ROW(3, lu1, NXTA, FBI, FB1, (void)0);                                      \
    if (__any(mism) && (tid & 63) == 0) atomicMax(&lastbad, IT);               \
    __syncthreads();                                                           \
    if (lastbad < IT) { conv_it = IT - 1; outP = CURA; goto done_label; }      \
}

__global__ __launch_bounds__(BLOCK, 4)
__attribute__((amdgpu_waves_per_eu(4, 4)))
void ldpc_kernel(const float* __restrict__ synd,
                 const float* __restrict__ llr0,
                 const int*  __restrict__ Vcol,
                 float* __restrict__ out)
{
    __shared__ __align__(16) int lvA[NW];   // 16 KB each; distinct objects so the
    __shared__ __align__(16) int lvB[NW];   // compiler can prove gather/scatter
    __shared__ __align__(16) int lvC[NW];   // independence and pipeline rows
    __shared__ int lastbad;

    const int b   = blockIdx.x;
    const int tid = threadIdx.x;
    const float* llr_b  = llr0 + (size_t)b * NN;
    const float* synd_b = synd + (size_t)b * MM;

    // ---- persistent register state (~41 regs, proven spill-free at the 64 cap) ----
    unsigned colp[RPT][6];    // 11 cols packed 2 x u16
    int synbits = 0;
    #pragma unroll
    for (int k = 0; k < RPT; ++k) {
        const int row = tid + k * BLOCK;
        const int4* cp = (const int4*)(Vcol + (size_t)row * DEG);
        int4 c0 = cp[0], c1 = cp[1], c2 = cp[2];
        const int cc[RDEG] = {c0.x,c0.y,c0.z,c0.w,c1.x,c1.y,c1.z,c1.w,c2.x,c2.y,c2.z};
        #pragma unroll
        for (int p = 0; p < 5; ++p)
            colp[k][p] = (unsigned)cc[2*p] | ((unsigned)cc[2*p+1] << 16);
        colp[k][5] = (unsigned)cc[10];
        synbits |= ((synd_b[row] != 0.0f) ? 1 : 0) << k;
    }

    // ---- u0 in 4 named scalars; thread owns words 4t..4t+3 ----
    int u0a, u0b, u0c, u0d;
    {
        const float2* lp = (const float2*)llr_b;
        float2 f0 = lp[4*tid+0], f1 = lp[4*tid+1], f2 = lp[4*tid+2], f3 = lp[4*tid+3];
        u0a = (quantI(f0.x) + BIAS) | ((quantI(f0.y) + BIAS) << 16);
        u0b = (quantI(f1.x) + BIAS) | ((quantI(f1.y) + BIAS) << 16);
        u0c = (quantI(f2.x) + BIAS) | ((quantI(f2.y) + BIAS) << 16);
        u0d = (quantI(f3.x) + BIAS) | ((quantI(f3.y) + BIAS) << 16);
        ((int4*)lvB)[tid] = make_int4(u0a, u0b, u0c, u0d);   // it=1 scatter target
    }
    if (tid == 0) lastbad = 1;

    // ---- msg init: message0 = u0[col], one-time scattered global gather ----
    unsigned msgp[RPT][3];
    #pragma unroll
    for (int k = 0; k < RPT; ++k) {
        unsigned nm[3] = {0u, 0u, 0u};
        #pragma unroll
        for (int d = 0; d < RDEG; ++d) {
            const int col = EX_COL(k, d);
            const int m = quantI(llr_b[col]);
            nm[d >> 2] |= ((unsigned)m & 0xffu) << ((d & 3) * 8);
        }
        msgp[k][0] = nm[0]; msgp[k][1] = nm[1]; msgp[k][2] = nm[2];
    }
    __syncthreads();

    int conv_it = 0;
    const int* outP = nullptr;

    // ---- it = 1 (special): scatter b1 into lvB; reset lvC for it2 ----
    {
        ROW1(0); ROW1(1); ROW1(2); ROW1(3);
        ((int4*)lvC)[tid] = make_int4(u0a, u0b, u0c, u0d);
        __syncthreads();
    }

    // ---- it = 2..8, buffer rotation period 3, fully compile-time ----
    ITER(2, lvB, lvC, lvA, 12, false);
    ITER(3, lvC, lvA, lvB, 14, false);
    ITER(4, lvA, lvB, lvC, 15, false);
    ITER(5, lvB, lvC, lvA, 15, true);
    ITER(6, lvC, lvA, lvB, 15, true);
    ITER(7, lvA, lvB, lvC, 15, true);
    ITER(8, lvB, lvC, lvA, 15, true);

    // ---- fell through: final parity check on l_v(8) (in lvC) ----
    {
        const unsigned short* curS = (const unsigned short*)lvC;
        int mism = 0;
        #pragma unroll
        for (int k = 0; k < RPT; ++k) {
            int par = 0;
            #pragma unroll
            for (int d = 0; d < RDEG; ++d)
                par ^= (curS[EX_COL(k, d)] <= BIAS) ? 1 : 0;
            mism |= par ^ ((synbits >> k) & 1);
        }
        if (__any(mism) && (tid & 63) == 0) atomicMax(&lastbad, MAXIT + 1);
        __syncthreads();
        if (lastbad < MAXIT + 1) conv_it = MAXIT;
        outP = lvC;
    }

done_label: ;
    // ---- outputs: [e_out | num_iters | l_out | converges], float32 flat ----
    const int   num = conv_it ? conv_it : MAXIT;
    const float cv  = conv_it ? 1.0f : 0.0f;
    float* e_out   = out;
    float* num_out = out + (size_t)BB * NN;
    float* l_out   = num_out + BB;
    float* c_out   = l_out + (size_t)BB * NN;
    #pragma unroll
    for (int j = 0; j < 4; ++j) {
        const int w  = tid + j * BLOCK;
        const int wv = outP[w];
        const int l0 = (wv & 0xffff) - BIAS;
        const int l1 = ((wv >> 16) & 0xffff) - BIAS;
        float2 e, l;
        e.x = (l0 <= 0) ? 1.0f : 0.0f;
        e.y = (l1 <= 0) ? 1.0f : 0.0f;
        l.x = (float)clamp8(l0) * 0.0625f;
        l.y = (float)clamp8(l1) * 0.0625f;
        ((float2*)(e_out + (size_t)b * NN))[w] = e;
        ((float2*)(l_out + (size_t)b * NN))[w] = l;
    }
    if (tid == 0) { num_out[b] = (float)num; c_out[b] = cv; }
}

extern "C" void kernel_launch(void* const* d_in, const int* in_sizes, int n_in,
                              void* d_out, int out_size, void* d_ws, size_t ws_size,
                              hipStream_t stream) {
    (void)in_sizes; (void)n_in; (void)d_ws; (void)ws_size; (void)out_size;
    const float* synd = (const float*)d_in[0];
    const float* llr0 = (const float*)d_in[1];
    const int*   Vcol = (const int*)d_in[3];   // V_c_col
    float*       out  = (float*)d_out;
    ldpc_kernel<<<BB, BLOCK, 0, stream>>>(synd, llr0, Vcol, out);
}

// Round 9
// 104.643 us; speedup vs baseline: 2.5501x; 2.5501x over previous
//
#include <hip/hip_runtime.h>

#define BB     128
#define MM     4096
#define NN     8192
#define DEG    12
#define RDEG   11          // edges 0..10 real; edge 11 is ALWAYS the dummy (col==NN)
#define MAXIT  8
#define BLOCK  1024
#define RPT    (MM / BLOCK)
#define NW     (NN / 2)    // l_v packed: 2 vars per word, u16 halves biased +32768
#define BIAS   32768
#define BIG    (1 << 20)

__device__ __forceinline__ int quantI(float x) {   // fp2fxp -> integer units of 1/16
    float r = rintf(x * 16.0f);                    // RNE, matches jnp.round
    r = fminf(r, 127.0f);
    r = fmaxf(r, -128.0f);
    return (int)r;
}
__device__ __forceinline__ int clamp8(int t) { return max(-128, min(127, t)); }
__device__ __forceinline__ int rne4(int t) {       // RNE of t/16, t >= 0
    const int r = t >> 4, rem = t & 15;
    return r + (((rem > 8) || (rem == 8 && (r & 1))) ? 1 : 0);
}

// Columns live in LDS (u16), not registers: frees the 24 persistent VGPRs that
// made R8 spill. One row = 12 u16 = 24 B -> three ds_read_b64 per row.
struct Cols { ushort4 a, b, c; };
__device__ __forceinline__ Cols loadCols(const unsigned short* colT, int row) {
    const ushort4* p = (const ushort4*)(colT + row * DEG);
    Cols C; C.a = p[0]; C.b = p[1]; C.c = p[2]; return C;
}
__device__ __forceinline__ int colOf(const Cols& C, int d) {
    switch (d) {
        case 0: return C.a.x; case 1: return C.a.y; case 2: return C.a.z; case 3: return C.a.w;
        case 4: return C.b.x; case 5: return C.b.y; case 6: return C.b.z; case 7: return C.b.w;
        case 8: return C.c.x; case 9: return C.c.y; default: return C.c.z;
    }
}

// One check-row (it >= 2). LU holds the 11 prefetched l_v halfwords. NEXTCODE
// (issued after aa[] collapses into eqb, i.e. at minimum register pressure)
// issues the NEXT row's gathers + the row-after-next's col read.
#define ROW(KK, LU, CC_, NXTA, FBI, FB1, NEXTCODE) do {                        \
    int sbits = 0, par = 0, min0 = BIG, min1 = BIG;                            \
    int aa[RDEG];                                                              \
    _Pragma("unroll") for (int d = 0; d < RDEG; ++d) {                         \
        const int m = (int)(signed char)((msgp[KK][d >> 2] >> ((d & 3) * 8)) & 0xffu); \
        const int l = LU[d] - BIAS;                                            \
        par ^= (l <= 0);                                                       \
        const int av = clamp8(l - m);                                          \
        const int t = abs(av);                                                 \
        sbits |= (av <= 0) << d;                                               \
        min1 = min(min1, max(min0, t)); min0 = min(min0, t);                   \
        aa[d] = t; }                                                           \
    /* dummy edge a = fxp(inf-0) = 7.9375 -> 127: joins mins AND clamps both */\
    min1 = min(min1, max(min0, 127)); min0 = min(min0, 127);                   \
    mism |= par ^ ((synbits >> KK) & 1);                                       \
    int eqb = 0;                                                               \
    _Pragma("unroll") for (int d = 0; d < RDEG; ++d)                           \
        eqb |= (aa[d] == min0) << d;                                           \
    NEXTCODE;                                                                  \
    const int qsb = ((synbits >> KK) & 1) ^ (__popc(sbits) & 1);               \
    const int q0 = FB1 ? min0 : rne4(min0 * FBI);                              \
    const int q1 = FB1 ? min1 : rne4(min1 * FBI);                              \
    unsigned nm0 = 0u, nm1 = 0u, nm2 = 0u;                                     \
    _Pragma("unroll") for (int d = 0; d < RDEG; ++d) {                         \
        const int q = ((eqb >> d) & 1) ? q1 : q0;                              \
        const int s = ((sbits >> d) & 1) ^ qsb;                                \
        const int bv = s ? -q : q;                                             \
        if (d < 4)      nm0 |= ((unsigned)bv & 0xffu) << (d * 8);              \
        else if (d < 8) nm1 |= ((unsigned)bv & 0xffu) << ((d - 4) * 8);        \
        else            nm2 |= ((unsigned)bv & 0xffu) << ((d - 8) * 8);        \
        if (bv != 0) {                                                         \
            const int col = colOf(CC_, d);                                     \
            atomicAdd(&NXTA[col >> 1], (int)((unsigned)bv << ((col & 1) << 4))); } } \
    msgp[KK][0] = nm0; msgp[KK][1] = nm1; msgp[KK][2] = nm2;                   \
} while (0)

// it == 1: a = message0 (already in msgp); no gathers/parity; dummy = +inf
// (excluded from mins, explicit 127 clamp); scatter b1 into lvB (holds u0).
#define ROW1(KK, CC_) do {                                                     \
    int sbits = 0, min0 = BIG, min1 = BIG;                                     \
    int aa[RDEG];                                                              \
    _Pragma("unroll") for (int d = 0; d < RDEG; ++d) {                         \
        const int m = (int)(signed char)((msgp[KK][d >> 2] >> ((d & 3) * 8)) & 0xffu); \
        const int t = abs(m);                                                  \
        sbits |= (m <= 0) << d;                                                \
        min1 = min(min1, max(min0, t)); min0 = min(min0, t);                   \
        aa[d] = t; }                                                           \
    int eqb = 0;                                                               \
    _Pragma("unroll") for (int d = 0; d < RDEG; ++d)                           \
        eqb |= (aa[d] == min0) << d;                                           \
    const int qsb = ((synbits >> KK) & 1) ^ (__popc(sbits) & 1);               \
    const int m0C = min(min0, 127), m1C = min(min1, 127);                      \
    const int q0 = rne4(m0C * 8);                                              \
    const int q1 = rne4(m1C * 8);                                              \
    unsigned nm0 = 0u, nm1 = 0u, nm2 = 0u;                                     \
    _Pragma("unroll") for (int d = 0; d < RDEG; ++d) {                         \
        const int q = ((eqb >> d) & 1) ? q1 : q0;                              \
        const int s = ((sbits >> d) & 1) ^ qsb;                                \
        const int bv = s ? -q : q;                                             \
        if (d < 4)      nm0 |= ((unsigned)bv & 0xffu) << (d * 8);              \
        else if (d < 8) nm1 |= ((unsigned)bv & 0xffu) << ((d - 4) * 8);        \
        else            nm2 |= ((unsigned)bv & 0xffu) << ((d - 8) * 8);        \
        if (bv != 0) {                                                         \
            const int col = colOf(CC_, d);                                     \
            atomicAdd(&lvB[col >> 1], (int)((unsigned)bv << ((col & 1) << 4))); } } \
    msgp[KK][0] = nm0; msgp[KK][1] = nm1; msgp[KK][2] = nm2;                   \
} while (0)

// One iteration (it >= 2), buffers bound at compile time (rotation period 3).
// Software pipeline: cols one row ahead (ds_read_b64x3), gathers issued in the
// previous row's compute tail, reset write hoisted to the head.
#define ITER(IT, CURA, NXTA, RSTA, FBI, FB1) {                                 \
    const unsigned short* curS = (const unsigned short*)CURA;                  \
    int mism = 0;                                                              \
    Cols c0 = loadCols(colT, tid);                                             \
    int luA[RDEG], luB[RDEG];                                                  \
    _Pragma("unroll") for (int d = 0; d < RDEG; ++d)                           \
        luA[d] = (int)curS[colOf(c0, d)];                                      \
    Cols c1 = loadCols(colT, tid + BLOCK);                                     \
    ((int4*)RSTA)[tid] = make_int4(u0a, u0b, u0c, u0d);                        \
    Cols c2, c3;                                                               \
    ROW(0, luA, c0, NXTA, FBI, FB1, {                                          \
        _Pragma("unroll") for (int d = 0; d < RDEG; ++d)                       \
            luB[d] = (int)curS[colOf(c1, d)];                                  \
        c2 = loadCols(colT, tid + 2 * BLOCK); });                              \
    ROW(1, luB, c1, NXTA, FBI, FB1, {                                          \
        _Pragma("unroll") for (int d = 0; d < RDEG; ++d)                       \
            luA[d] = (int)curS[colOf(c2, d)];                                  \
        c3 = loadCols(colT, tid + 3 * BLOCK); });                              \
    ROW(2, luA, c2, NXTA, FBI, FB1, {                                          \
        _Pragma("unroll") for (int d = 0; d < RDEG; ++d)                       \
            luB[d] = (int)curS[colOf(c3, d)]; });                              \
    ROW(3, luB, c3, NXTA, FBI, FB1, {});                                       \
    if (__any(mism) && (tid & 63) == 0) atomicMax(&lastbad, IT);               \
    __syncthreads();                                                           \
    if (lastbad < IT) { conv_it = IT - 1; outP = CURA; goto done_label; }      \
}

__global__ __launch_bounds__(BLOCK, 4)
__attribute__((amdgpu_waves_per_eu(4, 4)))
void ldpc_kernel(const float* __restrict__ synd,
                 const float* __restrict__ llr0,
                 const int*  __restrict__ Vcol,
                 float* __restrict__ out)
{
    __shared__ __align__(16) int lvA[NW];                 // 16 KB each
    __shared__ __align__(16) int lvB[NW];
    __shared__ __align__(16) int lvC[NW];
    __shared__ __align__(16) unsigned short colT[MM * DEG];  // 96 KB column table
    __shared__ int lastbad;                               // total ~147.5 KB LDS

    const int b   = blockIdx.x;
    const int tid = threadIdx.x;
    const float* llr_b  = llr0 + (size_t)b * NN;
    const float* synd_b = synd + (size_t)b * MM;

    // ---- fill colT from global (coalesced int4 reads, u16 LDS writes) ----
    {
        const int4* vg = (const int4*)Vcol;      // 12288 int4s
        ushort4*    ct = (ushort4*)colT;         // 12288 ushort4 slots
        #pragma unroll
        for (int j = 0; j < 12; ++j) {
            const int idx = tid + j * BLOCK;
            const int4 v = vg[idx];
            ushort4 s;
            s.x = (unsigned short)v.x; s.y = (unsigned short)v.y;
            s.z = (unsigned short)v.z; s.w = (unsigned short)v.w;
            ct[idx] = s;
        }
    }

    // ---- syndrome bits ----
    int synbits = 0;
    #pragma unroll
    for (int k = 0; k < RPT; ++k)
        synbits |= ((synd_b[tid + k * BLOCK] != 0.0f) ? 1 : 0) << k;

    // ---- u0 in 4 named scalars; thread owns words 4t..4t+3; lvB = u0 ----
    int u0a, u0b, u0c, u0d;
    {
        const float2* lp = (const float2*)llr_b;
        float2 f0 = lp[4*tid+0], f1 = lp[4*tid+1], f2 = lp[4*tid+2], f3 = lp[4*tid+3];
        u0a = (quantI(f0.x) + BIAS) | ((quantI(f0.y) + BIAS) << 16);
        u0b = (quantI(f1.x) + BIAS) | ((quantI(f1.y) + BIAS) << 16);
        u0c = (quantI(f2.x) + BIAS) | ((quantI(f2.y) + BIAS) << 16);
        u0d = (quantI(f3.x) + BIAS) | ((quantI(f3.y) + BIAS) << 16);
        ((int4*)lvB)[tid] = make_int4(u0a, u0b, u0c, u0d);   // it=1 scatter target
    }
    if (tid == 0) lastbad = 1;
    __syncthreads();   // colT + lvB visible

    // ---- msg0 = fxp(llr0)[col]: cols from LDS, values via global gather ----
    unsigned msgp[RPT][3];
    #pragma unroll
    for (int k = 0; k < RPT; ++k) {
        const Cols C = loadCols(colT, tid + k * BLOCK);
        unsigned nm[3] = {0u, 0u, 0u};
        #pragma unroll
        for (int d = 0; d < RDEG; ++d) {
            const int col = colOf(C, d);
            const int m = quantI(llr_b[col]);        // one-time, L2-resident
            nm[d >> 2] |= ((unsigned)m & 0xffu) << ((d & 3) * 8);
        }
        msgp[k][0] = nm[0]; msgp[k][1] = nm[1]; msgp[k][2] = nm[2];
    }

    int conv_it = 0;
    const int* outP = nullptr;

    // ---- it = 1: scatter b1 into lvB (=u0); reset lvC for it=2 ----
    {
        const Cols c0 = loadCols(colT, tid);
        const Cols c1 = loadCols(colT, tid + BLOCK);
        const Cols c2 = loadCols(colT, tid + 2 * BLOCK);
        const Cols c3 = loadCols(colT, tid + 3 * BLOCK);
        ROW1(0, c0); ROW1(1, c1); ROW1(2, c2); ROW1(3, c3);
        ((int4*)lvC)[tid] = make_int4(u0a, u0b, u0c, u0d);
        __syncthreads();
    }

    // ---- it = 2..8, rotation period 3, fully compile-time buffers ----
    ITER(2, lvB, lvC, lvA, 12, false);
    ITER(3, lvC, lvA, lvB, 14, false);
    ITER(4, lvA, lvB, lvC, 15, false);
    ITER(5, lvB, lvC, lvA, 15, true);
    ITER(6, lvC, lvA, lvB, 15, true);
    ITER(7, lvA, lvB, lvC, 15, true);
    ITER(8, lvB, lvC, lvA, 15, true);

    // ---- fell through: final parity check on l_v(8) (in lvC) ----
    {
        const unsigned short* curS = (const unsigned short*)lvC;
        int mism = 0;
        #pragma unroll
        for (int k = 0; k < RPT; ++k) {
            const Cols C = loadCols(colT, tid + k * BLOCK);
            int par = 0;
            #pragma unroll
            for (int d = 0; d < RDEG; ++d)
                par ^= (curS[colOf(C, d)] <= BIAS);
            mism |= par ^ ((synbits >> k) & 1);
        }
        if (__any(mism) && (tid & 63) == 0) atomicMax(&lastbad, MAXIT + 1);
        __syncthreads();
        if (lastbad < MAXIT + 1) conv_it = MAXIT;
        outP = lvC;
    }

done_label: ;
    // ---- outputs: [e_out | num_iters | l_out | converges], float32 flat ----
    const int   num = conv_it ? conv_it : MAXIT;
    const float cv  = conv_it ? 1.0f : 0.0f;
    float* e_out   = out;
    float* num_out = out + (size_t)BB * NN;
    float* l_out   = num_out + BB;
    float* c_out   = l_out + (size_t)BB * NN;
    #pragma unroll
    for (int j = 0; j < 4; ++j) {
        const int w  = tid + j * BLOCK;
        const int wv = outP[w];
        const int l0 = (wv & 0xffff) - BIAS;
        const int l1 = ((wv >> 16) & 0xffff) - BIAS;
        float2 e, l;
        e.x = (l0 <= 0) ? 1.0f : 0.0f;
        e.y = (l1 <= 0) ? 1.0f : 0.0f;
        l.x = (float)clamp8(l0) * 0.0625f;
        l.y = (float)clamp8(l1) * 0.0625f;
        ((float2*)(e_out + (size_t)b * NN))[w] = e;
        ((float2*)(l_out + (size_t)b * NN))[w] = l;
    }
    if (tid == 0) { num_out[b] = (float)num; c_out[b] = cv; }
}

extern "C" void kernel_launch(void* const* d_in, const int* in_sizes, int n_in,
                              void* d_out, int out_size, void* d_ws, size_t ws_size,
                              hipStream_t stream) {
    (void)in_sizes; (void)n_in; (void)d_ws; (void)ws_size; (void)out_size;
    const float* synd = (const float*)d_in[0];
    const float* llr0 = (const float*)d_in[1];
    const int*   Vcol = (const int*)d_in[3];   // V_c_col
    float*       out  = (float*)d_out;
    ldpc_kernel<<<BB, BLOCK, 0, stream>>>(synd, llr0, Vcol, out);
}

// Round 10
// 100.420 us; speedup vs baseline: 2.6573x; 1.0421x over previous
//
#include <hip/hip_runtime.h>

#define BB     128
#define MM     4096
#define NN     8192
#define DEG    12
#define RDEG   11          // edges 0..10 real; edge 11 is ALWAYS the dummy (col==NN)
#define MAXIT  8
#define BLOCK  1024
#define RPT    (MM / BLOCK)
#define NW     (NN / 2)    // l_v packed: 2 vars per word, u16 halves biased +32768
#define BIAS   32768
#define BIG    (1 << 20)

__device__ __forceinline__ int quantI(float x) {   // fp2fxp -> integer units of 1/16
    float r = rintf(x * 16.0f);                    // RNE, matches jnp.round
    r = fminf(r, 127.0f);
    r = fmaxf(r, -128.0f);
    return (int)r;
}
__device__ __forceinline__ int clamp8(int t) { return max(-128, min(127, t)); }
__device__ __forceinline__ int rne4(int t) {       // RNE of t/16, t >= 0
    const int r = t >> 4, rem = t & 15;
    return r + (((rem > 8) || (rem == 8 && (r & 1))) ? 1 : 0);
}

// Columns live in LDS (u16). One row = 12 u16 = 24 B -> three ds_read_b64.
struct Cols { ushort4 a, b, c; };
__device__ __forceinline__ Cols loadCols(const unsigned short* colT, int row) {
    const ushort4* p = (const ushort4*)(colT + row * DEG);
    Cols C; C.a = p[0]; C.b = p[1]; C.c = p[2]; return C;
}
__device__ __forceinline__ int colOf(const Cols& C, int d) {
    switch (d) {
        case 0: return C.a.x; case 1: return C.a.y; case 2: return C.a.z; case 3: return C.a.w;
        case 4: return C.b.x; case 5: return C.b.y; case 6: return C.b.z; case 7: return C.b.w;
        case 8: return C.c.x; case 9: return C.c.y; default: return C.c.z;
    }
}

// One check-row. FIRSTF==1: it=1 (m=0, so a = u0[col] = message0; dummy = +inf
// excluded from mins; no parity/mism). Else: dummy joins mins as 127, parity of
// l_v(it-1) fused into the gather, msg subtracted. NEXTCODE runs at the register
// low point (aa[] collapsed into eqb) and issues the next row's gathers.
#define ROW(KK, FIRSTF, LU, CC_, NXTA, FBI, FB1, NEXTCODE) do {                \
    int sbits = 0, par = 0, min0 = BIG, min1 = BIG;                            \
    int aa[RDEG];                                                              \
    _Pragma("unroll") for (int d = 0; d < RDEG; ++d) {                         \
        const int m = FIRSTF ? 0 :                                             \
            (int)(signed char)((msgp[KK][d >> 2] >> ((d & 3) * 8)) & 0xffu);   \
        const int l = LU[d] - BIAS;                                            \
        par ^= (l <= 0);                                                       \
        const int av = clamp8(l - m);                                          \
        const int t = abs(av);                                                 \
        sbits |= (av <= 0) << d;                                               \
        min1 = min(min1, max(min0, t)); min0 = min(min0, t);                   \
        aa[d] = t; }                                                           \
    if (!FIRSTF) {                                                             \
        /* dummy edge a = fxp(inf-0) = 7.9375 -> 127: joins mins, clamps both */\
        min1 = min(min1, max(min0, 127)); min0 = min(min0, 127);               \
        mism |= par ^ ((synbits >> KK) & 1); }                                 \
    int eqb = 0;                                                               \
    _Pragma("unroll") for (int d = 0; d < RDEG; ++d)                           \
        eqb |= (aa[d] == min0) << d;                                           \
    NEXTCODE;                                                                  \
    const int qsb = ((synbits >> KK) & 1) ^ (__popc(sbits) & 1);               \
    const int m0C = FIRSTF ? min(min0, 127) : min0;  /* non-first already <=127 */ \
    const int m1C = FIRSTF ? min(min1, 127) : min1;                            \
    const int q0 = FB1 ? m0C : rne4(m0C * FBI);                                \
    const int q1 = FB1 ? m1C : rne4(m1C * FBI);                                \
    unsigned nm0 = 0u, nm1 = 0u, nm2 = 0u;                                     \
    _Pragma("unroll") for (int d = 0; d < RDEG; ++d) {                         \
        const int q = ((eqb >> d) & 1) ? q1 : q0;                              \
        const int s = ((sbits >> d) & 1) ^ qsb;                                \
        const int bv = s ? -q : q;                                             \
        if (d < 4)      nm0 |= ((unsigned)bv & 0xffu) << (d * 8);              \
        else if (d < 8) nm1 |= ((unsigned)bv & 0xffu) << ((d - 4) * 8);        \
        else            nm2 |= ((unsigned)bv & 0xffu) << ((d - 8) * 8);        \
        if (bv != 0) {                                                         \
            const int col = colOf(CC_, d);                                     \
            atomicAdd(&NXTA[col >> 1], (int)((unsigned)bv << ((col & 1) << 4))); } } \
    msgp[KK][0] = nm0; msgp[KK][1] = nm1; msgp[KK][2] = nm2;                   \
} while (0)

// One iteration. c0,c1 are PERSISTENT and already valid at entry (prefetched
// before the previous barrier) -> row-0 gathers issue immediately after the
// barrier. ROW(3)'s tail reloads c0,c1 for the NEXT iteration (colT is static,
// so reading it before the barrier is race-free).
#define ITER(IT, FIRSTF, HAVERST, CURA, NXTA, RSTA, FBI, FB1) {                \
    const unsigned short* curS = (const unsigned short*)(CURA);                \
    int mism = 0; (void)mism;                                                  \
    int luA[RDEG], luB[RDEG];                                                  \
    _Pragma("unroll") for (int d = 0; d < RDEG; ++d)                           \
        luA[d] = (int)curS[colOf(c0, d)];                                      \
    if (HAVERST) ((int4*)(RSTA))[tid] = make_int4(u0a, u0b, u0c, u0d);         \
    Cols c2, c3;                                                               \
    ROW(0, FIRSTF, luA, c0, NXTA, FBI, FB1, {                                  \
        _Pragma("unroll") for (int d = 0; d < RDEG; ++d)                       \
            luB[d] = (int)curS[colOf(c1, d)];                                  \
        c2 = loadCols(colT, tid + 2 * BLOCK); });                              \
    ROW(1, FIRSTF, luB, c1, NXTA, FBI, FB1, {                                  \
        _Pragma("unroll") for (int d = 0; d < RDEG; ++d)                       \
            luA[d] = (int)curS[colOf(c2, d)];                                  \
        c3 = loadCols(colT, tid + 3 * BLOCK); });                              \
    ROW(2, FIRSTF, luA, c2, NXTA, FBI, FB1, {                                  \
        _Pragma("unroll") for (int d = 0; d < RDEG; ++d)                       \
            luB[d] = (int)curS[colOf(c3, d)]; });                              \
    ROW(3, FIRSTF, luB, c3, NXTA, FBI, FB1, {                                  \
        c0 = loadCols(colT, tid);                                              \
        c1 = loadCols(colT, tid + BLOCK); });                                  \
    if (!FIRSTF) {                                                             \
        if (__any(mism) && (tid & 63) == 0) atomicMax(&lastbad, IT);           \
    }                                                                          \
    __syncthreads();                                                           \
    if (!FIRSTF && lastbad < IT) { conv_it = IT - 1; outP = CURA; goto done_label; } \
}

__global__ __launch_bounds__(BLOCK, 4)
__attribute__((amdgpu_waves_per_eu(4, 4)))
void ldpc_kernel(const float* __restrict__ synd,
                 const float* __restrict__ llr0,
                 const int*  __restrict__ Vcol,
                 float* __restrict__ out)
{
    __shared__ __align__(16) int lvA[NW];                    // 16 KB each
    __shared__ __align__(16) int lvB[NW];
    __shared__ __align__(16) int lvC[NW];
    __shared__ __align__(16) unsigned short colT[MM * DEG];  // 96 KB column table
    __shared__ int lastbad;                                  // total ~148 KB LDS

    const int b   = blockIdx.x;
    const int tid = threadIdx.x;
    const float* llr_b  = llr0 + (size_t)b * NN;
    const float* synd_b = synd + (size_t)b * MM;

    // ---- fill colT from global (coalesced int4 reads, ushort4 LDS writes) ----
    {
        const int4* vg = (const int4*)Vcol;      // 12288 int4s
        ushort4*    ct = (ushort4*)colT;
        #pragma unroll
        for (int j = 0; j < 12; ++j) {
            const int idx = tid + j * BLOCK;
            const int4 v = vg[idx];
            ushort4 s;
            s.x = (unsigned short)v.x; s.y = (unsigned short)v.y;
            s.z = (unsigned short)v.z; s.w = (unsigned short)v.w;
            ct[idx] = s;
        }
    }

    // ---- syndrome bits ----
    int synbits = 0;
    #pragma unroll
    for (int k = 0; k < RPT; ++k)
        synbits |= ((synd_b[tid + k * BLOCK] != 0.0f) ? 1 : 0) << k;

    // ---- u0 in 4 named scalars; thread owns words 4t..4t+3; lvA = lvB = u0 ----
    int u0a, u0b, u0c, u0d;
    {
        const float4* lp = (const float4*)llr_b;
        float4 f0 = lp[2 * tid], f1 = lp[2 * tid + 1];
        u0a = (quantI(f0.x) + BIAS) | ((quantI(f0.y) + BIAS) << 16);
        u0b = (quantI(f0.z) + BIAS) | ((quantI(f0.w) + BIAS) << 16);
        u0c = (quantI(f1.x) + BIAS) | ((quantI(f1.y) + BIAS) << 16);
        u0d = (quantI(f1.z) + BIAS) | ((quantI(f1.w) + BIAS) << 16);
        ((int4*)lvA)[tid] = make_int4(u0a, u0b, u0c, u0d);   // it=1 scatter target
        ((int4*)lvB)[tid] = make_int4(u0a, u0b, u0c, u0d);   // it=1 gather source
    }
    if (tid == 0) lastbad = 1;

    // msg history starts at 0: it=1's gather of u0 then IS message0.
    unsigned msgp[RPT][3];
    #pragma unroll
    for (int k = 0; k < RPT; ++k) { msgp[k][0] = 0u; msgp[k][1] = 0u; msgp[k][2] = 0u; }

    __syncthreads();   // colT + lvA/lvB visible

    Cols c0 = loadCols(colT, tid);
    Cols c1 = loadCols(colT, tid + BLOCK);

    int conv_it = 0;
    const int* outP = nullptr;

    // ---- it = 1..8; rotation: NXT is always u0 at entry, RST preps it+1 ----
    ITER(1, 1, 0, lvB, lvA, lvC, 8,  false);   // lvA = l_v(1); lvB stays u0
    ITER(2, 0, 1, lvA, lvB, lvC, 12, false);   // lvB = l_v(2); lvC -> u0
    ITER(3, 0, 1, lvB, lvC, lvA, 14, false);
    ITER(4, 0, 1, lvC, lvA, lvB, 15, false);
    ITER(5, 0, 1, lvA, lvB, lvC, 15, true);
    ITER(6, 0, 1, lvB, lvC, lvA, 15, true);
    ITER(7, 0, 1, lvC, lvA, lvB, 15, true);
    ITER(8, 0, 0, lvA, lvB, lvC, 15, true);    // l_v(8) -> lvB; no reset needed

    // ---- fell through: final parity check on l_v(8) (in lvB) ----
    {
        const unsigned short* curS = (const unsigned short*)lvB;
        const Cols d2 = loadCols(colT, tid + 2 * BLOCK);
        const Cols d3 = loadCols(colT, tid + 3 * BLOCK);
        int mism = 0;
        {
            int par = 0;
            #pragma unroll
            for (int d = 0; d < RDEG; ++d) par ^= (curS[colOf(c0, d)] <= BIAS);
            mism |= par ^ (synbits & 1);
        }
        {
            int par = 0;
            #pragma unroll
            for (int d = 0; d < RDEG; ++d) par ^= (curS[colOf(c1, d)] <= BIAS);
            mism |= par ^ ((synbits >> 1) & 1);
        }
        {
            int par = 0;
            #pragma unroll
            for (int d = 0; d < RDEG; ++d) par ^= (curS[colOf(d2, d)] <= BIAS);
            mism |= par ^ ((synbits >> 2) & 1);
        }
        {
            int par = 0;
            #pragma unroll
            for (int d = 0; d < RDEG; ++d) par ^= (curS[colOf(d3, d)] <= BIAS);
            mism |= par ^ ((synbits >> 3) & 1);
        }
        if (__any(mism) && (tid & 63) == 0) atomicMax(&lastbad, MAXIT + 1);
        __syncthreads();
        if (lastbad < MAXIT + 1) conv_it = MAXIT;
        outP = lvB;
    }

done_label: ;
    // ---- outputs: [e_out | num_iters | l_out | converges], float32 flat ----
    const int   num = conv_it ? conv_it : MAXIT;
    const float cv  = conv_it ? 1.0f : 0.0f;
    float* e_out   = out;
    float* num_out = out + (size_t)BB * NN;
    float* l_out   = num_out + BB;
    float* c_out   = l_out + (size_t)BB * NN;
    #pragma unroll
    for (int j = 0; j < 4; ++j) {
        const int w  = tid + j * BLOCK;
        const int wv = outP[w];
        const int l0 = (wv & 0xffff) - BIAS;
        const int l1 = ((wv >> 16) & 0xffff) - BIAS;
        float2 e, l;
        e.x = (l0 <= 0) ? 1.0f : 0.0f;
        e.y = (l1 <= 0) ? 1.0f : 0.0f;
        l.x = (float)clamp8(l0) * 0.0625f;
        l.y = (float)clamp8(l1) * 0.0625f;
        ((float2*)(e_out + (size_t)b * NN))[w] = e;
        ((float2*)(l_out + (size_t)b * NN))[w] = l;
    }
    if (tid == 0) { num_out[b] = (float)num; c_out[b] = cv; }
}

extern "C" void kernel_launch(void* const* d_in, const int* in_sizes, int n_in,
                              void* d_out, int out_size, void* d_ws, size_t ws_size,
                              hipStream_t stream) {
    (void)in_sizes; (void)n_in; (void)d_ws; (void)ws_size; (void)out_size;
    const float* synd = (const float*)d_in[0];
    const float* llr0 = (const float*)d_in[1];
    const int*   Vcol = (const int*)d_in[3];   // V_c_col
    float*       out  = (float*)d_out;
    ldpc_kernel<<<BB, BLOCK, 0, stream>>>(synd, llr0, Vcol, out);
}